// Round 7
// baseline (159.340 us; speedup 1.0000x reference)
//
#include <hip/hip_runtime.h>

// MaskTypeProbabilitiesLayer: per (b,t) produce 8-wide 0/1 mask (int32 output).
//   gt = in[b,t,0]  (int32, 0..7)
//   base = TYPE_TABLE[gt]; for gt in {4,5,6} use dynamic mask based on whether
//   a 5 (timesign) / 6 (tempo) appeared at any position <= min(t+1, L-1).
//   Only zero/nonzero of the cumsum matters -> first-occurrence index per row.
//
// Bit-packed masks (bit j = feature j):
//   TYPE_TABLE[0]=0x02 [1]=0x06 [2]=0x10 [3]=0xF8 [7]=0x80 others=0
//   NO_TIMESIGN=0x20  NO_TEMPO=0x40  FULL=0xF8
//
// R6 tuning: block 256->512 (4 pos/thread). Grid-limited occupancy was the
// bottleneck (1024 blocks x 4 waves = 50% cap, measured 26%, 2.05 TB/s).
// 512-thread blocks give 8192 waves total = 100% device wave capacity,
// 4 blocks/CU for cross-barrier overlap.

#define SEQ_L 2048
#define NF 11
#define BLOCK 512
#define PER_THREAD (SEQ_L / BLOCK)   // 4

__global__ __launch_bounds__(BLOCK)
void mask_type_prob_kernel(const int* __restrict__ in, int* __restrict__ out) {
    __shared__ int s_gt[SEQ_L];
    __shared__ int s_first5;
    __shared__ int s_first6;

    const int b   = blockIdx.x;
    const int tid = threadIdx.x;

    if (tid == 0) { s_first5 = 0x7FFFFFFF; s_first6 = 0x7FFFFFFF; }
    __syncthreads();

    const int* row = in + (size_t)b * SEQ_L * NF;

    int g[PER_THREAD];
    #pragma unroll
    for (int k = 0; k < PER_THREAD; ++k) {
        const int t = tid + k * BLOCK;
        g[k] = row[(size_t)t * NF];   // stride-44B gather; lines contiguous per wave
    }

    int f5 = 0x7FFFFFFF, f6 = 0x7FFFFFFF;
    #pragma unroll
    for (int k = 0; k < PER_THREAD; ++k) {
        const int t = tid + k * BLOCK;
        s_gt[t] = g[k];
        if (g[k] == 5) f5 = min(f5, t);
        if (g[k] == 6) f6 = min(f6, t);
    }
    // Wave-level min-reduce, then one LDS atomic per wave.
    #pragma unroll
    for (int off = 32; off >= 1; off >>= 1) {
        f5 = min(f5, __shfl_xor(f5, off, 64));
        f6 = min(f6, __shfl_xor(f6, off, 64));
    }
    if ((tid & 63) == 0) {
        if (f5 != 0x7FFFFFFF) atomicMin(&s_first5, f5);
        if (f6 != 0x7FFFFFFF) atomicMin(&s_first6, f6);
    }
    __syncthreads();

    const int first5 = s_first5;
    const int first6 = s_first6;

    // base table entries 0..7, 8 bits each
    const unsigned long long pack = 0x80000000F8100602ULL;

    int* orow = out + (size_t)b * SEQ_L * 8;

    #pragma unroll
    for (int k = 0; k < PER_THREAD; ++k) {
        const int t = tid + k * BLOCK;
        const int gv = s_gt[t];
        unsigned m;
        if (gv >= 4 && gv <= 6) {
            const int idx = (t + 1 < SEQ_L - 1) ? (t + 1) : (SEQ_L - 1);
            m = (first5 > idx) ? 0x20u : ((first6 > idx) ? 0x40u : 0xF8u);
        } else {
            int gc = gv < 0 ? 0 : (gv > 8 ? 8 : gv);
            m = (gc >= 8) ? 0u : (unsigned)((pack >> (gc * 8)) & 0xFFu);
        }
        int4 lo, hi;
        lo.x = (int)((m >> 0) & 1u);
        lo.y = (int)((m >> 1) & 1u);
        lo.z = (int)((m >> 2) & 1u);
        lo.w = (int)((m >> 3) & 1u);
        hi.x = (int)((m >> 4) & 1u);
        hi.y = (int)((m >> 5) & 1u);
        hi.z = (int)((m >> 6) & 1u);
        hi.w = (int)((m >> 7) & 1u);
        int4* dst = (int4*)(orow + (size_t)t * 8);
        dst[0] = lo;
        dst[1] = hi;
    }
}

extern "C" void kernel_launch(void* const* d_in, const int* in_sizes, int n_in,
                              void* d_out, int out_size, void* d_ws, size_t ws_size,
                              hipStream_t stream) {
    const int* in = (const int*)d_in[0];
    int* out = (int*)d_out;
    const int batch = in_sizes[0] / (SEQ_L * NF);   // 1024
    mask_type_prob_kernel<<<batch, BLOCK, 0, stream>>>(in, out);
}

// Round 8
// 159.207 us; speedup vs baseline: 1.0008x; 1.0008x over previous
//
#include <hip/hip_runtime.h>

// MaskTypeProbabilitiesLayer: per (b,t) produce 8-wide 0/1 mask (int32 output).
//   gt = in[b,t,0]  (int32, 0..7)
//   base = TYPE_TABLE[gt]; for gt in {4,5,6} use dynamic mask based on whether
//   a 5 (timesign) / 6 (tempo) appeared at any position <= min(t+1, L-1).
//   Only zero/nonzero of the cumsum matters -> first-occurrence index per row.
//
// Bit-packed masks (bit j = feature j):
//   TYPE_TABLE[0]=0x02 [1]=0x06 [2]=0x10 [3]=0xF8 [7]=0x80 others=0
//   NO_TIMESIGN=0x20  NO_TEMPO=0x40  FULL=0xF8
//
// R7 history: 44B-stride gather read pinned BW at 2.0 TB/s regardless of
// occupancy (26% and 48% both -> 56 us) => per-CU read MLP ceiling, not TLP.
// R8 change: DENSE int4 streaming of the whole row (16B/lane, 11 loads/thread
// in flight) + in-register extraction of feature 0. Line traffic identical;
// MLP and access pattern match the 6.3 TB/s dense-copy regime.

#define SEQ_L 2048
#define NF 11
#define BLOCK 512
#define ROW_INT4 (SEQ_L * NF / 4)    // 5632 int4 chunks per row
#define PASSES (ROW_INT4 / BLOCK)    // 11
#define PER_THREAD (SEQ_L / BLOCK)   // 4 output positions per thread

__global__ __launch_bounds__(BLOCK)
void mask_type_prob_kernel(const int* __restrict__ in, int* __restrict__ out) {
    __shared__ int s_gt[SEQ_L];
    __shared__ int s_first5;
    __shared__ int s_first6;

    const int b   = blockIdx.x;
    const int tid = threadIdx.x;

    if (tid == 0) { s_first5 = 0x7FFFFFFF; s_first6 = 0x7FFFFFFF; }
    __syncthreads();

    // Dense stream of the full row: 5632 int4s, perfectly coalesced 1KB/wave.
    const int4* rowv = (const int4*)(in + (size_t)b * SEQ_L * NF);

    int f5 = 0x7FFFFFFF, f6 = 0x7FFFFFFF;
    #pragma unroll
    for (int p = 0; p < PASSES; ++p) {
        const int i4 = tid + p * BLOCK;      // chunk index 0..5631
        const int4 v = rowv[i4];
        const int j  = i4 * 4;               // int index of v.x within row
        // gt values live at int indices 11*m. This 4-int chunk contains one
        // iff mi = ceil(j/11) has 11*mi in [j, j+4). (44B spacing => at most 1.)
        const int mi  = (j + 10) / 11;
        const int pos = mi * 11 - j;         // 0..10
        if (pos < 4) {
            const int gv = (pos == 0) ? v.x : (pos == 1) ? v.y : (pos == 2) ? v.z : v.w;
            s_gt[mi] = gv;
            if (gv == 5) f5 = min(f5, mi);
            if (gv == 6) f6 = min(f6, mi);
        }
    }

    // Wave-level min-reduce, then one LDS atomic per wave.
    #pragma unroll
    for (int off = 32; off >= 1; off >>= 1) {
        f5 = min(f5, __shfl_xor(f5, off, 64));
        f6 = min(f6, __shfl_xor(f6, off, 64));
    }
    if ((tid & 63) == 0) {
        if (f5 != 0x7FFFFFFF) atomicMin(&s_first5, f5);
        if (f6 != 0x7FFFFFFF) atomicMin(&s_first6, f6);
    }
    __syncthreads();

    const int first5 = s_first5;
    const int first6 = s_first6;

    // base table entries 0..7, 8 bits each
    const unsigned long long pack = 0x80000000F8100602ULL;

    int* orow = out + (size_t)b * SEQ_L * 8;

    #pragma unroll
    for (int k = 0; k < PER_THREAD; ++k) {
        const int t = tid + k * BLOCK;
        const int gv = s_gt[t];
        unsigned m;
        if (gv >= 4 && gv <= 6) {
            const int idx = (t + 1 < SEQ_L - 1) ? (t + 1) : (SEQ_L - 1);
            m = (first5 > idx) ? 0x20u : ((first6 > idx) ? 0x40u : 0xF8u);
        } else {
            int gc = gv < 0 ? 0 : (gv > 8 ? 8 : gv);
            m = (gc >= 8) ? 0u : (unsigned)((pack >> (gc * 8)) & 0xFFu);
        }
        int4 lo, hi;
        lo.x = (int)((m >> 0) & 1u);
        lo.y = (int)((m >> 1) & 1u);
        lo.z = (int)((m >> 2) & 1u);
        lo.w = (int)((m >> 3) & 1u);
        hi.x = (int)((m >> 4) & 1u);
        hi.y = (int)((m >> 5) & 1u);
        hi.z = (int)((m >> 6) & 1u);
        hi.w = (int)((m >> 7) & 1u);
        int4* dst = (int4*)(orow + (size_t)t * 8);
        dst[0] = lo;
        dst[1] = hi;
    }
}

extern "C" void kernel_launch(void* const* d_in, const int* in_sizes, int n_in,
                              void* d_out, int out_size, void* d_ws, size_t ws_size,
                              hipStream_t stream) {
    const int* in = (const int*)d_in[0];
    int* out = (int*)d_out;
    const int batch = in_sizes[0] / (SEQ_L * NF);   // 1024
    mask_type_prob_kernel<<<batch, BLOCK, 0, stream>>>(in, out);
}

// Round 9
// 153.593 us; speedup vs baseline: 1.0374x; 1.0366x over previous
//
#include <hip/hip_runtime.h>

// MaskTypeProbabilitiesLayer: per (b,t) produce 8-wide 0/1 mask (int32 output).
//   gt = in[b,t,0]; base = TYPE_TABLE[gt]; gt in {4,5,6} -> dynamic mask from
//   whether a 5 / 6 appeared at any position <= min(t+1, L-1)  (== first-occ idx).
//
// Bit-packed masks: TYPE_TABLE[0]=0x02 [1]=0x06 [2]=0x10 [3]=0xF8 [7]=0x80;
//   NO_TIMESIGN=0x20 NO_TEMPO=0x40 FULL=0xF8.
//
// R8 post-mortem: VGPR_Count=12 proved the compiler serialized loads (1 line
// in flight/wave) -> ~2 TB/s regardless of access pattern or occupancy.
// R9: (a) explicit load-all-11-int4-then-consume register array forces
// batched issue (VGPR ~60, 11 lines in flight/thread);
// (b) stores made lane-dense: thread owns one 16B output chunk per pass
// (consecutive lanes -> consecutive 16B), mask recomputed per half-position.

#define SEQ_L 2048
#define NF 11
#define BLOCK 512
#define ROW_INT4 (SEQ_L * NF / 4)    // 5632 input int4 chunks per row
#define PASSES (ROW_INT4 / BLOCK)    // 11
#define OUT_INT4 (SEQ_L * 8 / 4)     // 4096 output int4 chunks per row
#define OPASS (OUT_INT4 / BLOCK)     // 8

__global__ __launch_bounds__(BLOCK)
void mask_type_prob_kernel(const int* __restrict__ in, int* __restrict__ out) {
    __shared__ int s_gt[SEQ_L];
    __shared__ int s_first5;
    __shared__ int s_first6;

    const int b   = blockIdx.x;
    const int tid = threadIdx.x;

    if (tid == 0) { s_first5 = 0x7FFFFFFF; s_first6 = 0x7FFFFFFF; }
    __syncthreads();

    const int4* rowv = (const int4*)(in + (size_t)b * SEQ_L * NF);

    // ---- Phase 1a: issue ALL 11 loads before any consumption (force MLP) ----
    int4 v[PASSES];
    #pragma unroll
    for (int p = 0; p < PASSES; ++p) {
        v[p] = rowv[tid + p * BLOCK];
    }

    // ---- Phase 1b: extract feature-0 values, stage to LDS, track first 5/6 ----
    int f5 = 0x7FFFFFFF, f6 = 0x7FFFFFFF;
    #pragma unroll
    for (int p = 0; p < PASSES; ++p) {
        const int i4 = tid + p * BLOCK;      // chunk index 0..5631
        const int j  = i4 * 4;               // int index of v[p].x within row
        // gt values sit at int indices 11*m; a 4-int chunk holds at most one.
        const int mi  = (j + 10) / 11;
        const int pos = mi * 11 - j;         // 0..10
        if (pos < 4) {
            const int gv = (pos == 0) ? v[p].x : (pos == 1) ? v[p].y
                         : (pos == 2) ? v[p].z : v[p].w;
            s_gt[mi] = gv;
            if (gv == 5) f5 = min(f5, mi);
            if (gv == 6) f6 = min(f6, mi);
        }
    }

    // Wave-level min-reduce, then one LDS atomic per wave.
    #pragma unroll
    for (int off = 32; off >= 1; off >>= 1) {
        f5 = min(f5, __shfl_xor(f5, off, 64));
        f6 = min(f6, __shfl_xor(f6, off, 64));
    }
    if ((tid & 63) == 0) {
        if (f5 != 0x7FFFFFFF) atomicMin(&s_first5, f5);
        if (f6 != 0x7FFFFFFF) atomicMin(&s_first6, f6);
    }
    __syncthreads();

    const int first5 = s_first5;
    const int first6 = s_first6;

    // base table entries 0..7, 8 bits each
    const unsigned long long pack = 0x80000000F8100602ULL;

    // ---- Phase 2: lane-dense stores. Chunk c = 16B half of position c>>1. ----
    int4* orowv = (int4*)(out + (size_t)b * SEQ_L * 8);

    #pragma unroll
    for (int k = 0; k < OPASS; ++k) {
        const int c    = tid + k * BLOCK;    // 0..4095; lanes contiguous
        const int t    = c >> 1;             // position
        const int half = c & 1;              // 0 = bits 0..3, 1 = bits 4..7
        const int gv   = s_gt[t];            // pairs of lanes broadcast-share
        unsigned m;
        if (gv >= 4 && gv <= 6) {
            const int idx = (t + 1 < SEQ_L - 1) ? (t + 1) : (SEQ_L - 1);
            m = (first5 > idx) ? 0x20u : ((first6 > idx) ? 0x40u : 0xF8u);
        } else {
            int gc = gv < 0 ? 0 : (gv > 8 ? 8 : gv);
            m = (gc >= 8) ? 0u : (unsigned)((pack >> (gc * 8)) & 0xFFu);
        }
        const unsigned nib = half ? (m >> 4) : m;
        int4 w;
        w.x = (int)((nib >> 0) & 1u);
        w.y = (int)((nib >> 1) & 1u);
        w.z = (int)((nib >> 2) & 1u);
        w.w = (int)((nib >> 3) & 1u);
        orowv[c] = w;
    }
}

extern "C" void kernel_launch(void* const* d_in, const int* in_sizes, int n_in,
                              void* d_out, int out_size, void* d_ws, size_t ws_size,
                              hipStream_t stream) {
    const int* in = (const int*)d_in[0];
    int* out = (int*)d_out;
    const int batch = in_sizes[0] / (SEQ_L * NF);   // 1024
    mask_type_prob_kernel<<<batch, BLOCK, 0, stream>>>(in, out);
}